// Round 10
// baseline (46.267 us; speedup 1.0000x reference)
//
#include <hip/hip_runtime.h>
#include <hip/hip_bf16.h>

#define HID 16
#define DIN 64
#define NK  32
#define NB  8192

#define WSTRIDE 36                       // floats per (k,d) hinge block: c[16] u[16] A B pad2
#define OUTER_OFF (NK * DIN * WSTRIDE)   // outer-net hinge blocks start here

typedef float v4f __attribute__((ext_vector_type(4)));

// ---- Kernel A: hinge-form weight transform (runs every launch; ~3 us) ----
// inner (k,d):  sum_h w2*relu(w1*x+b1) = A*x + B_d + sum_h u_h*|x + c_h|
// outer (k):    sum_h ow2*relu(ow1*s+ob1) + ob2 = Ao*s + Bo + sum_h uo|s+co|
__global__ void prep_kernel(
    const float* __restrict__ iw1, const float* __restrict__ ib1,
    const float* __restrict__ iw2, const float* __restrict__ ib2,
    const float* __restrict__ ow1, const float* __restrict__ ob1,
    const float* __restrict__ ow2, const float* __restrict__ ob2,
    float* __restrict__ ws)
{
    const int tid = blockIdx.x * 256 + threadIdx.x;
    if (tid < NK * DIN) {
        // one thread per (k,d); [K,D,HID] layout -> base = tid*HID
        const float* w1p = iw1 + tid * HID;
        const float* b1p = ib1 + tid * HID;
        const float* w2p = iw2 + tid * HID;
        float* o = ws + tid * WSTRIDE;
        float A = 0.f, B = ib2[tid];
        #pragma unroll
        for (int h = 0; h < HID; ++h) {
            const float w1 = w1p[h], b1 = b1p[h], w2 = w2p[h];
            A = fmaf(0.5f * w2, w1, A);
            B = fmaf(0.5f * w2, b1, B);
            const float aw = fabsf(w1);
            const bool ok = aw > 1e-20f;
            o[h]       = ok ? b1 / w1 : 0.f;
            o[16 + h]  = ok ? 0.5f * w2 * aw : 0.f;
            if (!ok) B = fmaf(0.5f * w2, fabsf(b1), B);
        }
        o[32] = A; o[33] = B; o[34] = 0.f; o[35] = 0.f;
    } else if (tid < NK * DIN + NK) {
        const int k = tid - NK * DIN;
        const float* w1p = ow1 + k * HID;
        const float* b1p = ob1 + k * HID;
        const float* w2p = ow2 + k * HID;
        float* o = ws + OUTER_OFF + k * WSTRIDE;
        float A = 0.f, B = ob2[k];
        #pragma unroll
        for (int h = 0; h < HID; ++h) {
            const float w1 = w1p[h], b1 = b1p[h], w2 = w2p[h];
            A = fmaf(0.5f * w2, w1, A);
            B = fmaf(0.5f * w2, b1, B);
            const float aw = fabsf(w1);
            const bool ok = aw > 1e-20f;
            o[h]       = ok ? b1 / w1 : 0.f;
            o[16 + h]  = ok ? 0.5f * w2 * aw : 0.f;
            if (!ok) B = fmaf(0.5f * w2, fabsf(b1), B);
        }
        o[32] = A; o[33] = B; o[34] = 0.f; o[35] = 0.f;
    }
}

// ---- Kernel B: lane = batch row. Inner loop has ZERO vector-memory / DS ops:
// x row lives in 16 float4 VGPRs; hinge weights come in on the scalar pipe
// (lane-uniform address -> s_load). Every VALU op reads at most 1 SGPR, so no
// s->v mov bloat. sk is lane-private: no reduction, no LDS, no shuffles.
__global__ __launch_bounds__(256, 4) void kan_main(
    const float* __restrict__ x,
    const float* __restrict__ ws,
    float* __restrict__ out)
{
    const int t    = threadIdx.x;
    const int lane = t & 63;
    const int wid  = t >> 6;
    const int k    = blockIdx.x & (NK - 1);
    const int row  = (blockIdx.x >> 5) * 256 + wid * 64 + lane;

    // one-time transposed x load: 16 dwordx4, prologue-only cost
    v4f xw[16];
    const v4f* xr = (const v4f*)(x + row * DIN);
    #pragma unroll
    for (int q = 0; q < 16; ++q) xw[q] = xr[q];

    const float* __restrict__ wk = ws + (k * DIN) * WSTRIDE;  // lane-uniform

    float acc0 = 0.f, acc1 = 0.f;

    #pragma unroll 2
    for (int dq = 0; dq < 16; ++dq) {
        #pragma unroll
        for (int j = 0; j < 4; ++j) {
            const int d = dq * 4 + j;
            const float xv = xw[dq][j];
            const float* __restrict__ wd = wk + d * WSTRIDE;
            acc0 = fmaf(wd[32], xv, acc0);   // A*x   (1 SGPR)
            acc1 += wd[33];                  // + B_d (1 SGPR)
            #pragma unroll
            for (int h = 0; h < HID; h += 2) {
                acc0 = fmaf(fabsf(xv + wd[h]),     wd[16 + h],     acc0);
                acc1 = fmaf(fabsf(xv + wd[h + 1]), wd[16 + h + 1], acc1);
            }
        }
    }
    const float sk = acc0 + acc1;

    // outer net, hinge form (weights on scalar pipe as well)
    const float* __restrict__ wo = ws + OUTER_OFF + k * WSTRIDE;
    float oa = 0.f, ob = 0.f;
    #pragma unroll
    for (int h = 0; h < HID; h += 2) {
        oa = fmaf(fabsf(sk + wo[h]),     wo[16 + h],     oa);
        ob = fmaf(fabsf(sk + wo[h + 1]), wo[16 + h + 1], ob);
    }
    oa = fmaf(wo[32], sk, oa);
    ob += wo[33];

    out[row * NK + k] = oa + ob;
}

extern "C" void kernel_launch(void* const* d_in, const int* in_sizes, int n_in,
                              void* d_out, int out_size, void* d_ws, size_t ws_size,
                              hipStream_t stream) {
    const float* x   = (const float*)d_in[0];
    const float* iw1 = (const float*)d_in[1];
    const float* ib1 = (const float*)d_in[2];
    const float* iw2 = (const float*)d_in[3];
    const float* ib2 = (const float*)d_in[4];
    const float* ow1 = (const float*)d_in[5];
    const float* ob1 = (const float*)d_in[6];
    const float* ow2 = (const float*)d_in[7];
    const float* ob2 = (const float*)d_in[8];
    float* ws  = (float*)d_ws;
    float* out = (float*)d_out;

    // A: transform weights to hinge form (2080 active threads)
    prep_kernel<<<9, 256, 0, stream>>>(iw1, ib1, iw2, ib2, ow1, ob1, ow2, ob2, ws);
    // B: main compute, 1024 blocks x 256
    const int grid = (NB / 256) * NK;
    kan_main<<<grid, 256, 0, stream>>>(x, ws, out);
}

// Round 11
// 33.959 us; speedup vs baseline: 1.3625x; 1.3625x over previous
//
#include <hip/hip_runtime.h>
#include <hip/hip_bf16.h>

#define HID 16
#define DIN 64
#define NK  32
#define NB  8192

#define WSTRIDE 36                       // floats per (k,d) hinge block: c[16] u[16] A B pad2
#define OUTER_OFF (NK * DIN * WSTRIDE)   // outer-net hinge blocks start here

typedef float v4f __attribute__((ext_vector_type(4)));

// ---- Kernel A: hinge-form weight transform (~3 us, every launch) ----
// inner (k,d):  sum_h w2*relu(w1*x+b1) = A*x + B_d + sum_h u_h*|x + c_h|
// outer (k):    sum_h ow2*relu(ow1*s+ob1) + ob2 = Ao*s + Bo + sum_h uo|s+co|
__global__ void prep_kernel(
    const float* __restrict__ iw1, const float* __restrict__ ib1,
    const float* __restrict__ iw2, const float* __restrict__ ib2,
    const float* __restrict__ ow1, const float* __restrict__ ob1,
    const float* __restrict__ ow2, const float* __restrict__ ob2,
    float* __restrict__ ws)
{
    const int tid = blockIdx.x * 256 + threadIdx.x;
    if (tid < NK * DIN) {
        const float* w1p = iw1 + tid * HID;
        const float* b1p = ib1 + tid * HID;
        const float* w2p = iw2 + tid * HID;
        float* o = ws + tid * WSTRIDE;
        float A = 0.f, B = ib2[tid];
        #pragma unroll
        for (int h = 0; h < HID; ++h) {
            const float w1 = w1p[h], b1 = b1p[h], w2 = w2p[h];
            A = fmaf(0.5f * w2, w1, A);
            B = fmaf(0.5f * w2, b1, B);
            const float aw = fabsf(w1);
            const bool ok = aw > 1e-20f;
            o[h]       = ok ? b1 / w1 : 0.f;
            o[16 + h]  = ok ? 0.5f * w2 * aw : 0.f;
            if (!ok) B = fmaf(0.5f * w2, fabsf(b1), B);
        }
        o[32] = A; o[33] = B; o[34] = 0.f; o[35] = 0.f;
    } else if (tid < NK * DIN + NK) {
        const int k = tid - NK * DIN;
        const float* w1p = ow1 + k * HID;
        const float* b1p = ob1 + k * HID;
        const float* w2p = ow2 + k * HID;
        float* o = ws + OUTER_OFF + k * WSTRIDE;
        float A = 0.f, B = ob2[k];
        #pragma unroll
        for (int h = 0; h < HID; ++h) {
            const float w1 = w1p[h], b1 = b1p[h], w2 = w2p[h];
            A = fmaf(0.5f * w2, w1, A);
            B = fmaf(0.5f * w2, b1, B);
            const float aw = fabsf(w1);
            const bool ok = aw > 1e-20f;
            o[h]       = ok ? b1 / w1 : 0.f;
            o[16 + h]  = ok ? 0.5f * w2 * aw : 0.f;
            if (!ok) B = fmaf(0.5f * w2, fabsf(b1), B);
        }
        o[32] = A; o[33] = B; o[34] = 0.f; o[35] = 0.f;
    }
}

// ---- Kernel B: lane = batch row. FULLY-unrolled d loop -> xw[] is statically
// indexed and stays in 64 VGPRs (round-10 bug: runtime dq sent it to scratch).
// Inner loop: zero VMEM, zero DS. Weights arrive on the scalar pipe (s_load,
// lane-uniform address); every VALU op reads <= 1 SGPR -> no s->v movs.
// sk is lane-private: no reduction anywhere.
__global__ __launch_bounds__(256, 4) void kan_main(
    const float* __restrict__ x,
    const float* __restrict__ ws,
    float* __restrict__ out)
{
    const int t    = threadIdx.x;
    const int lane = t & 63;
    const int wid  = t >> 6;
    const int k    = blockIdx.x & (NK - 1);
    const int row  = (blockIdx.x >> 5) * 256 + wid * 64 + lane;

    // one-time x row load: 16 dwordx4 (prologue-only)
    v4f xw[16];
    const v4f* xr = (const v4f*)(x + row * DIN);
    #pragma unroll
    for (int q = 0; q < 16; ++q) xw[q] = xr[q];

    const float* __restrict__ wk = ws + (k * DIN) * WSTRIDE;  // lane-uniform

    float acc0 = 0.f, acc1 = 0.f;

    #pragma unroll
    for (int dq = 0; dq < 16; ++dq) {
        #pragma unroll
        for (int j = 0; j < 4; ++j) {
            const int d = dq * 4 + j;          // compile-time constant
            const float xv = xw[dq][j];        // static register subindex
            const float* __restrict__ wd = wk + d * WSTRIDE;
            acc0 = fmaf(wd[32], xv, acc0);     // A*x   (1 SGPR)
            acc1 += wd[33];                    // + B_d (1 SGPR)
            #pragma unroll
            for (int h = 0; h < HID; h += 2) {
                acc0 = fmaf(fabsf(xv + wd[h]),     wd[16 + h],     acc0);
                acc1 = fmaf(fabsf(xv + wd[h + 1]), wd[16 + h + 1], acc1);
            }
        }
    }
    const float sk = acc0 + acc1;

    // outer net, hinge form
    const float* __restrict__ wo = ws + OUTER_OFF + k * WSTRIDE;
    float oa = 0.f, ob = 0.f;
    #pragma unroll
    for (int h = 0; h < HID; h += 2) {
        oa = fmaf(fabsf(sk + wo[h]),     wo[16 + h],     oa);
        ob = fmaf(fabsf(sk + wo[h + 1]), wo[16 + h + 1], ob);
    }
    oa = fmaf(wo[32], sk, oa);
    ob += wo[33];

    out[row * NK + k] = oa + ob;
}

extern "C" void kernel_launch(void* const* d_in, const int* in_sizes, int n_in,
                              void* d_out, int out_size, void* d_ws, size_t ws_size,
                              hipStream_t stream) {
    const float* x   = (const float*)d_in[0];
    const float* iw1 = (const float*)d_in[1];
    const float* ib1 = (const float*)d_in[2];
    const float* iw2 = (const float*)d_in[3];
    const float* ib2 = (const float*)d_in[4];
    const float* ow1 = (const float*)d_in[5];
    const float* ob1 = (const float*)d_in[6];
    const float* ow2 = (const float*)d_in[7];
    const float* ob2 = (const float*)d_in[8];
    float* ws  = (float*)d_ws;
    float* out = (float*)d_out;

    prep_kernel<<<9, 256, 0, stream>>>(iw1, ib1, iw2, ib2, ow1, ob1, ow2, ob2, ws);
    const int grid = (NB / 256) * NK;  // 1024 blocks
    kan_main<<<grid, 256, 0, stream>>>(x, ws, out);
}